// Round 8
// baseline (2284.089 us; speedup 1.0000x reference)
//
#include <hip/hip_runtime.h>

// GraphSAGE link predictor, bf16-MFMA + bucketed-LDS-aggregation edition.
//   h = relu( mean_agg(x)@w1l.T + b1 + x@w1r.T )
//   z = mean_agg(h)@w2l.T + b2 + h@w2r.T
//   out[e] = dot(z[src[e]], z[dst[e]])
//
// R5: bf16 MFMA GEMMs. R6: bf16 z + fused layer-1 (agg-then-project K=256).
// R7 FAILED: nontemporal loads — nt on the 16-lane-broadcast csr_src read
//     bypassed L1 broadcast (+100MB fetch in agg); nt killed 8x cross-pass dst
//     reuse in count/fill. Lesson: nt only for single-use non-broadcast streams.
// R8: exact CSR deleted. Coarse-bucket edges by 128-node dst tile (4B packed
//     records), then aggregate per-bucket in LDS fp32 (ds_add_f32, +1 pad and
//     rotated col order -> <=2-way bank alias = free). Degree counted in the
//     same pass. Removes count_deg(50us)+fill_csr(75us)+scans and their write
//     amplification; bucket_fill writes ~64B-dense runs.
//
// edge_index arrives as int32 (harness converts int64 inputs).

#define IN_C      128
#define HID_C     128
#define OUT_C     64
#define NB_MAX    1024      // max dst tiles (N <= 131072)
#define NFILL     128       // blocks in hist/fill passes

typedef unsigned short u16;
typedef __attribute__((ext_vector_type(8))) __bf16 bf16x8;
typedef __attribute__((ext_vector_type(4))) float f32x4;

__device__ inline u16 f2bf(float f) {                 // RNE f32 -> bf16
    unsigned u = __float_as_uint(f);
    u += 0x7fff + ((u >> 16) & 1);
    return (u16)(u >> 16);
}
__device__ inline float bflo(unsigned v) { return __uint_as_float(v << 16); }
__device__ inline float bfhi(unsigned v) { return __uint_as_float(v & 0xffff0000u); }

// ---------------------------------------------------------------- bucket build
__global__ __launch_bounds__(256) void bucket_hist(const int* __restrict__ dst,
                                                   int* __restrict__ ghist,
                                                   int E, int nb) {
    __shared__ int lh[NB_MAX];
    const int t = threadIdx.x;
    for (int i = t; i < nb; i += 256) lh[i] = 0;
    __syncthreads();
    const int slice = (E + NFILL - 1) / NFILL;
    const int e1 = min(E, (int)(blockIdx.x + 1) * slice);
    for (int e = blockIdx.x * slice + t; e < e1; e += 256)
        atomicAdd(&lh[dst[e] >> 7], 1);
    __syncthreads();
    for (int i = t; i < nb; i += 256)
        if (lh[i]) atomicAdd(&ghist[i], lh[i]);
}

// single block: exclusive scan of ghist[0..nb) -> off, gcur
__global__ __launch_bounds__(256) void bucket_scan(const int* __restrict__ ghist,
                                                   int* __restrict__ off,
                                                   int* __restrict__ gcur, int nb) {
    __shared__ int sd[256];
    const int t = threadIdx.x;
    int v[4];
    int s = 0;
#pragma unroll
    for (int j = 0; j < 4; ++j) {
        int i = t * 4 + j;
        v[j] = (i < nb) ? ghist[i] : 0;
        s += v[j];
    }
    int own = s;
    sd[t] = s;
    __syncthreads();
    for (int o = 1; o < 256; o <<= 1) {
        int vv = 0;
        if (t >= o) vv = sd[t - o];
        __syncthreads();
        sd[t] += vv;
        __syncthreads();
    }
    int base = sd[t] - own;
#pragma unroll
    for (int j = 0; j < 4; ++j) {
        int i = t * 4 + j;
        if (i < nb) { off[i] = base; gcur[i] = base; }
        base += v[j];
    }
}

// scatter packed records (src<<7 | dst&127) into buckets; per-block LDS
// reservation keeps each block's writes dense (~64B runs per bucket).
__global__ __launch_bounds__(256) void bucket_fill(const int* __restrict__ ei,
                                                   int* __restrict__ gcur,
                                                   unsigned* __restrict__ buckets,
                                                   int E, int nb) {
    __shared__ int lh[NB_MAX];
    __shared__ int lbase[NB_MAX];
    __shared__ int lcur[NB_MAX];
    const int t = threadIdx.x;
    for (int i = t; i < nb; i += 256) { lh[i] = 0; lcur[i] = 0; }
    __syncthreads();
    const int slice = (E + NFILL - 1) / NFILL;
    const int e0 = blockIdx.x * slice;
    const int e1 = min(E, e0 + slice);
    for (int e = e0 + t; e < e1; e += 256)
        atomicAdd(&lh[ei[(size_t)E + e] >> 7], 1);
    __syncthreads();
    for (int i = t; i < nb; i += 256)
        if (lh[i]) lbase[i] = atomicAdd(&gcur[i], lh[i]);
    __syncthreads();
    for (int e = e0 + t; e < e1; e += 256) {
        int d = ei[(size_t)E + e];
        int s = ei[e];
        int b = d >> 7;
        int pos = lbase[b] + atomicAdd(&lcur[b], 1);
        buckets[pos] = ((unsigned)s << 7) | (unsigned)(d & 127);
    }
}

// ---------------------------------------------------------------- converts
__global__ __launch_bounds__(256) void cvt_x(const float* __restrict__ in,
                                             u16* __restrict__ outb, int n4) {
    int i = blockIdx.x * 256 + threadIdx.x;
    if (i >= n4) return;
    float4 v = ((const float4*)in)[i];
    ushort4 o;
    o.x = f2bf(v.x); o.y = f2bf(v.y); o.z = f2bf(v.z); o.w = f2bf(v.w);
    ((ushort4*)outb)[i] = o;
}

// Wb1[c][0:128]=w1l[c], Wb1[c][128:256]=w1r[c]  -> [128][256] bf16
// Wb2 = cat(w2l,w2r)                             -> [128][128] bf16
__global__ __launch_bounds__(256) void cvt_w(const float* __restrict__ w1l,
                                             const float* __restrict__ w1r,
                                             const float* __restrict__ w2l,
                                             const float* __restrict__ w2r,
                                             u16* __restrict__ Wb1,
                                             u16* __restrict__ Wb2) {
    int i = blockIdx.x * 256 + threadIdx.x;
    if (i < 32768) {
        int c = i >> 8, k = i & 255;
        float v = (k < 128) ? w1l[c * 128 + k] : w1r[c * 128 + (k - 128)];
        Wb1[i] = f2bf(v);
    } else if (i < 49152) {
        int j = i - 32768;
        float v = (j < 8192) ? w2l[j] : w2r[j - 8192];
        Wb2[j] = f2bf(v);
    }
}

// ---------------------------------------------------------------- bucketed aggregate
// block b aggregates dst nodes [b*128, b*128+128): LDS fp32 accum + deg count,
// epilogue: out = acc/max(deg,1) [+ other], written bf16.
template <int C, bool HAS_OTHER>
__global__ __launch_bounds__(256) void agg_lds(const u16* __restrict__ gl,
                                               const u16* __restrict__ other,
                                               const int* __restrict__ off,
                                               const int* __restrict__ ghist,
                                               const unsigned* __restrict__ buckets,
                                               u16* __restrict__ outp, int n) {
    constexpr int G      = C / 8;            // lanes per edge
    constexpr int STRIDE = C + 1;            // pad: spreads banks across dl
    __shared__ float acc[128 * STRIDE];
    __shared__ int   deg[128];

    const int t = threadIdx.x;
    const int node0 = blockIdx.x << 7;
    for (int i = t; i < 128 * STRIDE; i += 256) acc[i] = 0.f;
    if (t < 128) deg[t] = 0;
    __syncthreads();

    const int p0   = off[blockIdx.x];
    const int cntE = ghist[blockIdx.x];
    const int g = t / G, l = t % G;
    constexpr int NGRP = 256 / G;

    for (int i = g; i < cntE; i += NGRP) {
        unsigned rec = buckets[p0 + i];
        int src = (int)(rec >> 7);
        int dl  = (int)(rec & 127u);
        uint4 v = *(const uint4*)(gl + (size_t)src * C + l * 8);
        float vals[8] = {bflo(v.x), bfhi(v.x), bflo(v.y), bfhi(v.y),
                         bflo(v.z), bfhi(v.z), bflo(v.w), bfhi(v.w)};
        float* arow = &acc[dl * STRIDE + l * 8];
#pragma unroll
        for (int j = 0; j < 8; ++j) {        // rotate col order: <=2-way bank alias
            int jj = (j + l) & 7;
            atomicAdd(&arow[jj], vals[jj]);
        }
        if (l == 0) atomicAdd(&deg[dl], 1);
    }
    __syncthreads();

    for (int seg = t; seg < 128 * G; seg += 256) {
        int nd = seg / G, sc = seg % G;
        int gn = node0 + nd;
        if (gn >= n) continue;
        float id = 1.f / (float)max(deg[nd], 1);
        const float* ap = &acc[nd * STRIDE + sc * 8];
        float r[8];
#pragma unroll
        for (int j = 0; j < 8; ++j) r[j] = ap[j] * id;
        if (HAS_OTHER) {
            uint4 o = *(const uint4*)(other + (size_t)gn * C + sc * 8);
            r[0] += bflo(o.x); r[1] += bfhi(o.x);
            r[2] += bflo(o.y); r[3] += bfhi(o.y);
            r[4] += bflo(o.z); r[5] += bfhi(o.z);
            r[6] += bflo(o.w); r[7] += bfhi(o.w);
        }
        uint4 w;
        w.x = (unsigned)f2bf(r[0]) | ((unsigned)f2bf(r[1]) << 16);
        w.y = (unsigned)f2bf(r[2]) | ((unsigned)f2bf(r[3]) << 16);
        w.z = (unsigned)f2bf(r[4]) | ((unsigned)f2bf(r[5]) << 16);
        w.w = (unsigned)f2bf(r[6]) | ((unsigned)f2bf(r[7]) << 16);
        *(uint4*)(outp + (size_t)gn * C + sc * 8) = w;
    }
}

// ---------------------------------------------------------------- fused layer-1 GEMM
// h = relu([A0|A1] @ W.T + b), A0/A1 [n][128] bf16, W [128][256] bf16 -> h [n][128] bf16
// Frag facts (m89/m120): A[m=lane&15][k=quad*8+j], B[k=quad*8+j][n=lane&15],
// D: col=lane&15, row=quad*4+reg.
__global__ __launch_bounds__(256) void gemm_l1(const u16* __restrict__ A0,
                                               const u16* __restrict__ A1,
                                               const u16* __restrict__ Wb,
                                               const float* __restrict__ bias,
                                               u16* __restrict__ outp, int nrows) {
    constexpr int K    = 256;
    constexpr int COLS = 128;
    constexpr int KS   = K / 32;             // 8
    constexpr int NCT  = COLS / 16;          // 8
    constexpr int WROW = K + 8;
    __shared__ u16 wl[COLS * WROW];          // 67.6 KB

    const int t = threadIdx.x;
    for (int i = t; i < COLS * (K / 8); i += 256) {
        int r = i >> 5, p = i & 31;
        *(uint4*)&wl[r * WROW + p * 8] = *(const uint4*)&Wb[(size_t)r * K + p * 8];
    }
    __syncthreads();

    const int wv    = t >> 6;
    const int lane  = t & 63;
    const int cl    = lane & 15;
    const int quad  = lane >> 4;
    const int rbase = blockIdx.x * 128 + wv * 32;

    bf16x8 afrag[2][KS];
#pragma unroll
    for (int tile = 0; tile < 2; ++tile) {
        int r = min(rbase + tile * 16 + cl, nrows - 1);
        const u16* s0 = A0 + (size_t)r * 128 + quad * 8;
        const u16* s1 = A1 + (size_t)r * 128 + quad * 8;
#pragma unroll
        for (int ks = 0; ks < 4; ++ks) {
            afrag[tile][ks]     = *(const bf16x8*)(s0 + ks * 32);
            afrag[tile][4 + ks] = *(const bf16x8*)(s1 + ks * 32);
        }
    }

#pragma unroll
    for (int ct = 0; ct < NCT; ++ct) {
        f32x4 acc0 = {0.f, 0.f, 0.f, 0.f};
        f32x4 acc1 = {0.f, 0.f, 0.f, 0.f};
        const u16* wp = &wl[(ct * 16 + cl) * WROW + quad * 8];
#pragma unroll
        for (int ks = 0; ks < KS; ++ks) {
            bf16x8 bfrag = *(const bf16x8*)(wp + ks * 32);
            acc0 = __builtin_amdgcn_mfma_f32_16x16x32_bf16(afrag[0][ks], bfrag, acc0, 0, 0, 0);
            acc1 = __builtin_amdgcn_mfma_f32_16x16x32_bf16(afrag[1][ks], bfrag, acc1, 0, 0, 0);
        }
        int gc = ct * 16 + cl;
        float bv = bias[gc];
#pragma unroll
        for (int tile = 0; tile < 2; ++tile) {
            f32x4 a = tile ? acc1 : acc0;
#pragma unroll
            for (int r = 0; r < 4; ++r) {
                int row = rbase + tile * 16 + quad * 4 + r;
                if (row < nrows)
                    outp[(size_t)row * COLS + gc] = f2bf(fmaxf(a[r] + bv, 0.f));
            }
        }
    }
}

// ---------------------------------------------------------------- dual GEMM (layer 2)
// [outA | outB](bf16) = xb @ Wb.T ; outB += bias. Wb [2*COLS][K] bf16.
template <int K, int COLS>
__global__ __launch_bounds__(256) void gemm_mfma(const u16* __restrict__ xb,
                                                 const u16* __restrict__ Wb,
                                                 const float* __restrict__ bias,
                                                 u16* __restrict__ outA,
                                                 u16* __restrict__ outB,
                                                 int nrows) {
    constexpr int NCOL = 2 * COLS;
    constexpr int NCT  = NCOL / 16;
    constexpr int KS   = K / 32;
    constexpr int WROW = K + 8;
    __shared__ u16 wl[NCOL * WROW];

    const int t = threadIdx.x;
    for (int i = t; i < NCOL * (K / 8); i += 256) {
        int r = i / (K / 8), p = i % (K / 8);
        *(uint4*)&wl[r * WROW + p * 8] = *(const uint4*)&Wb[(size_t)r * K + p * 8];
    }
    __syncthreads();

    const int wv    = t >> 6;
    const int lane  = t & 63;
    const int cl    = lane & 15;
    const int quad  = lane >> 4;
    const int rbase = blockIdx.x * 128 + wv * 32;

    bf16x8 afrag[2][KS];
#pragma unroll
    for (int tile = 0; tile < 2; ++tile) {
        int r = rbase + tile * 16 + cl;
        const u16* src = xb + (size_t)min(r, nrows - 1) * K + quad * 8;
#pragma unroll
        for (int ks = 0; ks < KS; ++ks)
            afrag[tile][ks] = *(const bf16x8*)(src + ks * 32);
    }

#pragma unroll
    for (int ct = 0; ct < NCT; ++ct) {
        f32x4 acc0 = {0.f, 0.f, 0.f, 0.f};
        f32x4 acc1 = {0.f, 0.f, 0.f, 0.f};
        const u16* wp = &wl[(ct * 16 + cl) * WROW + quad * 8];
#pragma unroll
        for (int ks = 0; ks < KS; ++ks) {
            bf16x8 bfrag = *(const bf16x8*)(wp + ks * 32);
            acc0 = __builtin_amdgcn_mfma_f32_16x16x32_bf16(afrag[0][ks], bfrag, acc0, 0, 0, 0);
            acc1 = __builtin_amdgcn_mfma_f32_16x16x32_bf16(afrag[1][ks], bfrag, acc1, 0, 0, 0);
        }
        int gc = ct * 16 + cl;
        bool isA = gc < COLS;
        float bv = isA ? 0.f : bias[gc - COLS];
        u16* dst = isA ? (outA + gc) : (outB + (gc - COLS));
#pragma unroll
        for (int tile = 0; tile < 2; ++tile) {
            f32x4 a = tile ? acc1 : acc0;
#pragma unroll
            for (int r = 0; r < 4; ++r) {
                int row = rbase + tile * 16 + quad * 4 + r;
                if (row < nrows) dst[(size_t)row * COLS] = f2bf(a[r] + bv);
            }
        }
    }
}

// ---------------------------------------------------------------- decode (bf16 z)
// nt on the edge stream only: single-use, non-broadcast (R7 lesson).
__global__ __launch_bounds__(256) void decode(const u16* __restrict__ z,
                                              const int* __restrict__ ei,
                                              float* __restrict__ out, int E, int n) {
    int t = blockIdx.x * 256 + threadIdx.x;
    int e = t >> 3, l = t & 7;
    if (e >= E) return;
    int s = __builtin_nontemporal_load(ei + e);
    int d = __builtin_nontemporal_load(ei + (size_t)E + e);
    float p = 0.f;
    if ((unsigned)s < (unsigned)n && (unsigned)d < (unsigned)n) {
        uint4 a = *(const uint4*)(z + (size_t)s * OUT_C + l * 8);
        uint4 b = *(const uint4*)(z + (size_t)d * OUT_C + l * 8);
        p  = bflo(a.x) * bflo(b.x) + bfhi(a.x) * bfhi(b.x);
        p += bflo(a.y) * bflo(b.y) + bfhi(a.y) * bfhi(b.y);
        p += bflo(a.z) * bflo(b.z) + bfhi(a.z) * bfhi(b.z);
        p += bflo(a.w) * bflo(b.w) + bfhi(a.w) * bfhi(b.w);
    }
    p += __shfl_xor(p, 4);
    p += __shfl_xor(p, 2);
    p += __shfl_xor(p, 1);
    if (l == 0) out[e] = p;
}

// ---------------------------------------------------------------- launch
extern "C" void kernel_launch(void* const* d_in, const int* in_sizes, int n_in,
                              void* d_out, int out_size, void* d_ws, size_t ws_size,
                              hipStream_t stream) {
    const float* x   = (const float*)d_in[0];
    const int*   ei  = (const int*)d_in[1];
    const float* w1l = (const float*)d_in[2];
    const float* w1r = (const float*)d_in[3];
    const float* b1  = (const float*)d_in[4];
    const float* w2l = (const float*)d_in[5];
    const float* w2r = (const float*)d_in[6];
    const float* b2  = (const float*)d_in[7];
    float*       out = (float*)d_out;

    const int N  = in_sizes[0] / IN_C;
    const int E  = in_sizes[1] / 2;
    const int NB = (N + 127) >> 7;           // 782 dst tiles

    auto alignup = [](size_t v) { return (v + 255) & ~(size_t)255; };
    char* p = (char*)d_ws;
    int*      ghist   = (int*)p;      p += alignup((size_t)NB_MAX * 4);
    int*      boff    = (int*)p;      p += alignup((size_t)NB_MAX * 4);
    int*      gcur    = (int*)p;      p += alignup((size_t)NB_MAX * 4);
    unsigned* buckets = (unsigned*)p; p += alignup((size_t)E * 4);
    u16*      Wb1     = (u16*)p;      p += alignup((size_t)HID_C * 2 * IN_C * 2);
    u16*      Wb2     = (u16*)p;      p += alignup((size_t)2 * OUT_C * HID_C * 2);
    u16*      xb      = (u16*)p;      p += alignup((size_t)N * IN_C * 2);
    u16*      ag1     = (u16*)p;      p += alignup((size_t)N * HID_C * 2);
    u16*      hb      = (u16*)p;      p += alignup((size_t)N * HID_C * 2);
    u16*      hlb     = (u16*)p;      p += alignup((size_t)N * OUT_C * 2);
    u16*      hrb     = (u16*)p;      p += alignup((size_t)N * OUT_C * 2);
    u16*      zb      = (u16*)p;      p += alignup((size_t)N * OUT_C * 2);

    // converts (independent of buckets)
    cvt_x<<<(N * IN_C / 4 + 255) / 256, 256, 0, stream>>>(x, xb, N * IN_C / 4);
    cvt_w<<<192, 256, 0, stream>>>(w1l, w1r, w2l, w2r, Wb1, Wb2);

    // bucket build
    hipMemsetAsync(ghist, 0, (size_t)NB * 4, stream);
    bucket_hist<<<NFILL, 256, 0, stream>>>(ei + (size_t)E, ghist, E, NB);
    bucket_scan<<<1, 256, 0, stream>>>(ghist, boff, gcur, NB);
    bucket_fill<<<NFILL, 256, 0, stream>>>(ei, gcur, buckets, E, NB);

    const int rb = (N + 127) / 128;

    // ag1 = mean_agg(xb)   (LDS-accumulated per dst tile)
    agg_lds<HID_C, false><<<NB, 256, 0, stream>>>(xb, nullptr, boff, ghist,
                                                  buckets, ag1, N);
    // h = relu([ag1|xb] @ [w1l|w1r].T + b1)
    gemm_l1<<<rb, 256, 0, stream>>>(ag1, xb, Wb1, b1, hb, N);

    // hl = h@w2l.T ; hr = h@w2r.T + b2
    gemm_mfma<HID_C, OUT_C><<<rb, 256, 0, stream>>>(hb, Wb2, b2, hlb, hrb, N);
    // z = mean_agg(hl) + hr  (bf16)
    agg_lds<OUT_C, true><<<NB, 256, 0, stream>>>(hlb, hrb, boff, ghist,
                                                 buckets, zb, N);

    // decode (bf16 z)
    decode<<<((size_t)E * 8 + 255) / 256, 256, 0, stream>>>(zb, ei, out, E, N);
}

// Round 10
// 982.994 us; speedup vs baseline: 2.3236x; 2.3236x over previous
//
#include <hip/hip_runtime.h>

// GraphSAGE link predictor, bf16-MFMA + bucketed register-scan aggregation.
//   h = relu( mean_agg(x)@w1l.T + b1 + x@w1r.T )
//   z = mean_agg(h)@w2l.T + b2 + h@w2r.T
//   out[e] = dot(z[src[e]], z[dst[e]])
//
// R6 (valid 468us): exact CSR + agg_bf. R8: bucket build proven cheap+replay-safe,
//     but LDS-atomic agg = 1350us. R9 FAILED post-timing tripwire: counting-sort
//     agg (multi-barrier LDS sort) diverged on graph replays — unprovable sync
//     bug; discarded.
// R10: keep ONLY replay-proven kernels (bucket build from R8, gemms/decode/cvt
//     from R6/R8) + new agg_scan: NO shared mem, NO barriers, NO atomics.
//     Each wave walks the bucket record stream (wave-uniform broadcast loads);
//     16-lane groups predicate on node ownership and accumulate 8 nodes in
//     REGISTERS (deg in registers too). Race-free by construction.
//
// edge_index arrives as int32 (harness converts int64 inputs).

#define IN_C      128
#define HID_C     128
#define OUT_C     64
#define NB_MAX    1024      // max dst tiles (N <= 131072)
#define NFILL     128       // blocks in hist/fill passes

typedef unsigned short u16;
typedef __attribute__((ext_vector_type(8))) __bf16 bf16x8;
typedef __attribute__((ext_vector_type(4))) float f32x4;

__device__ inline u16 f2bf(float f) {                 // RNE f32 -> bf16
    unsigned u = __float_as_uint(f);
    u += 0x7fff + ((u >> 16) & 1);
    return (u16)(u >> 16);
}
__device__ inline float bflo(unsigned v) { return __uint_as_float(v << 16); }
__device__ inline float bfhi(unsigned v) { return __uint_as_float(v & 0xffff0000u); }

// ---------------------------------------------------------------- bucket build
__global__ __launch_bounds__(256) void bucket_hist(const int* __restrict__ dst,
                                                   int* __restrict__ ghist,
                                                   int E, int nb) {
    __shared__ int lh[NB_MAX];
    const int t = threadIdx.x;
    for (int i = t; i < nb; i += 256) lh[i] = 0;
    __syncthreads();
    const int slice = (E + NFILL - 1) / NFILL;
    const int e1 = min(E, (int)(blockIdx.x + 1) * slice);
    for (int e = blockIdx.x * slice + t; e < e1; e += 256)
        atomicAdd(&lh[dst[e] >> 7], 1);
    __syncthreads();
    for (int i = t; i < nb; i += 256)
        if (lh[i]) atomicAdd(&ghist[i], lh[i]);
}

// single block: exclusive scan of ghist[0..nb) -> off, gcur
__global__ __launch_bounds__(256) void bucket_scan(const int* __restrict__ ghist,
                                                   int* __restrict__ off,
                                                   int* __restrict__ gcur, int nb) {
    __shared__ int sd[256];
    const int t = threadIdx.x;
    int v[4];
    int s = 0;
#pragma unroll
    for (int j = 0; j < 4; ++j) {
        int i = t * 4 + j;
        v[j] = (i < nb) ? ghist[i] : 0;
        s += v[j];
    }
    int own = s;
    sd[t] = s;
    __syncthreads();
    for (int o = 1; o < 256; o <<= 1) {
        int vv = 0;
        if (t >= o) vv = sd[t - o];
        __syncthreads();
        sd[t] += vv;
        __syncthreads();
    }
    int base = sd[t] - own;
#pragma unroll
    for (int j = 0; j < 4; ++j) {
        int i = t * 4 + j;
        if (i < nb) { off[i] = base; gcur[i] = base; }
        base += v[j];
    }
}

// scatter packed records (src<<7 | dst&127) into buckets; per-block LDS
// reservation keeps each block's writes dense (~64B runs per bucket).
__global__ __launch_bounds__(256) void bucket_fill(const int* __restrict__ ei,
                                                   int* __restrict__ gcur,
                                                   unsigned* __restrict__ buckets,
                                                   int E, int nb) {
    __shared__ int lh[NB_MAX];
    __shared__ int lbase[NB_MAX];
    __shared__ int lcur[NB_MAX];
    const int t = threadIdx.x;
    for (int i = t; i < nb; i += 256) { lh[i] = 0; lcur[i] = 0; }
    __syncthreads();
    const int slice = (E + NFILL - 1) / NFILL;
    const int e0 = blockIdx.x * slice;
    const int e1 = min(E, e0 + slice);
    for (int e = e0 + t; e < e1; e += 256)
        atomicAdd(&lh[ei[(size_t)E + e] >> 7], 1);
    __syncthreads();
    for (int i = t; i < nb; i += 256)
        if (lh[i]) lbase[i] = atomicAdd(&gcur[i], lh[i]);
    __syncthreads();
    for (int e = e0 + t; e < e1; e += 256) {
        int d = ei[(size_t)E + e];
        int s = ei[e];
        int b = d >> 7;
        int pos = lbase[b] + atomicAdd(&lcur[b], 1);
        buckets[pos] = ((unsigned)s << 7) | (unsigned)(d & 127);
    }
}

// ---------------------------------------------------------------- converts
__global__ __launch_bounds__(256) void cvt_x(const float* __restrict__ in,
                                             u16* __restrict__ outb, int n4) {
    int i = blockIdx.x * 256 + threadIdx.x;
    if (i >= n4) return;
    float4 v = ((const float4*)in)[i];
    ushort4 o;
    o.x = f2bf(v.x); o.y = f2bf(v.y); o.z = f2bf(v.z); o.w = f2bf(v.w);
    ((ushort4*)outb)[i] = o;
}

// Wb1[c][0:128]=w1l[c], Wb1[c][128:256]=w1r[c]  -> [128][256] bf16
// Wb2 = cat(w2l,w2r)                             -> [128][128] bf16
__global__ __launch_bounds__(256) void cvt_w(const float* __restrict__ w1l,
                                             const float* __restrict__ w1r,
                                             const float* __restrict__ w2l,
                                             const float* __restrict__ w2r,
                                             u16* __restrict__ Wb1,
                                             u16* __restrict__ Wb2) {
    int i = blockIdx.x * 256 + threadIdx.x;
    if (i < 32768) {
        int c = i >> 8, k = i & 255;
        float v = (k < 128) ? w1l[c * 128 + k] : w1r[c * 128 + (k - 128)];
        Wb1[i] = f2bf(v);
    } else if (i < 49152) {
        int j = i - 32768;
        float v = (j < 8192) ? w2l[j] : w2r[j - 8192];
        Wb2[j] = f2bf(v);
    }
}

// ---------------------------------------------------------------- scan aggregate
// Block b owns dst nodes [b*128, (b+1)*128). Every wave walks the bucket's
// record stream with wave-uniform loads (L1 broadcast); each G-lane group
// predicates on ownership (dl mod NGRP == g) and accumulates its NPG nodes in
// registers; degree counted in registers. No LDS, no barriers, no atomics.
// out[n] = acc/max(deg,1) [+ other[n]], bf16.
template <int C, bool HAS_OTHER>
__global__ __launch_bounds__(256) void agg_scan(const u16* __restrict__ gl,
                                                const u16* __restrict__ other,
                                                const int* __restrict__ boff,
                                                const int* __restrict__ ghist,
                                                const unsigned* __restrict__ buckets,
                                                u16* __restrict__ outp, int n) {
    constexpr int G     = C / 8;             // lanes per group (16 / 8)
    constexpr int NGRP  = 256 / G;           // groups per block (16 / 32)
    constexpr int NPG   = 128 / NGRP;        // nodes per group (8 / 4)
    constexpr int LOG2N = (NGRP == 16) ? 4 : 5;

    const int t = threadIdx.x;
    const int node0 = blockIdx.x << 7;
    const int p0  = boff[blockIdx.x];
    const int tot = ghist[blockIdx.x];
    const int g = t / G, l = t % G;

    float acc[NPG][8];
    int   deg[NPG];
#pragma unroll
    for (int k = 0; k < NPG; ++k) {
        deg[k] = 0;
#pragma unroll
        for (int j = 0; j < 8; ++j) acc[k][j] = 0.f;
    }

    for (int j = 0; j < tot; ++j) {
        unsigned rec = buckets[p0 + j];      // wave-uniform -> 1 line, broadcast
        int dl = (int)(rec & 127u);
        if ((dl & (NGRP - 1)) == g) {
            int src = (int)(rec >> 7);
            int kk  = dl >> LOG2N;
            uint4 v = *(const uint4*)(gl + (size_t)src * C + l * 8);
            float f0 = bflo(v.x), f1 = bfhi(v.x), f2 = bflo(v.y), f3 = bfhi(v.y);
            float f4 = bflo(v.z), f5 = bfhi(v.z), f6 = bflo(v.w), f7 = bfhi(v.w);
#pragma unroll
            for (int k = 0; k < NPG; ++k) {
                if (k == kk) {
                    acc[k][0] += f0; acc[k][1] += f1;
                    acc[k][2] += f2; acc[k][3] += f3;
                    acc[k][4] += f4; acc[k][5] += f5;
                    acc[k][6] += f6; acc[k][7] += f7;
                    deg[k]++;
                }
            }
        }
    }

#pragma unroll
    for (int k = 0; k < NPG; ++k) {
        int nd = g + k * NGRP;
        int gn = node0 + nd;
        if (gn >= n) continue;
        float id = 1.f / (float)max(deg[k], 1);
        float r[8];
#pragma unroll
        for (int j = 0; j < 8; ++j) r[j] = acc[k][j] * id;
        if (HAS_OTHER) {
            uint4 o = *(const uint4*)(other + (size_t)gn * C + l * 8);
            r[0] += bflo(o.x); r[1] += bfhi(o.x);
            r[2] += bflo(o.y); r[3] += bfhi(o.y);
            r[4] += bflo(o.z); r[5] += bfhi(o.z);
            r[6] += bflo(o.w); r[7] += bfhi(o.w);
        }
        uint4 w;
        w.x = (unsigned)f2bf(r[0]) | ((unsigned)f2bf(r[1]) << 16);
        w.y = (unsigned)f2bf(r[2]) | ((unsigned)f2bf(r[3]) << 16);
        w.z = (unsigned)f2bf(r[4]) | ((unsigned)f2bf(r[5]) << 16);
        w.w = (unsigned)f2bf(r[6]) | ((unsigned)f2bf(r[7]) << 16);
        *(uint4*)(outp + (size_t)gn * C + l * 8) = w;
    }
}

// ---------------------------------------------------------------- fused layer-1 GEMM
// h = relu([A0|A1] @ W.T + b), A0/A1 [n][128] bf16, W [128][256] bf16 -> h [n][128] bf16
// Frag facts (m89/m120): A[m=lane&15][k=quad*8+j], B[k=quad*8+j][n=lane&15],
// D: col=lane&15, row=quad*4+reg.
__global__ __launch_bounds__(256) void gemm_l1(const u16* __restrict__ A0,
                                               const u16* __restrict__ A1,
                                               const u16* __restrict__ Wb,
                                               const float* __restrict__ bias,
                                               u16* __restrict__ outp, int nrows) {
    constexpr int K    = 256;
    constexpr int COLS = 128;
    constexpr int KS   = K / 32;             // 8
    constexpr int NCT  = COLS / 16;          // 8
    constexpr int WROW = K + 8;
    __shared__ u16 wl[COLS * WROW];          // 67.6 KB

    const int t = threadIdx.x;
    for (int i = t; i < COLS * (K / 8); i += 256) {
        int r = i >> 5, p = i & 31;
        *(uint4*)&wl[r * WROW + p * 8] = *(const uint4*)&Wb[(size_t)r * K + p * 8];
    }
    __syncthreads();

    const int wv    = t >> 6;
    const int lane  = t & 63;
    const int cl    = lane & 15;
    const int quad  = lane >> 4;
    const int rbase = blockIdx.x * 128 + wv * 32;

    bf16x8 afrag[2][KS];
#pragma unroll
    for (int tile = 0; tile < 2; ++tile) {
        int r = min(rbase + tile * 16 + cl, nrows - 1);
        const u16* s0 = A0 + (size_t)r * 128 + quad * 8;
        const u16* s1 = A1 + (size_t)r * 128 + quad * 8;
#pragma unroll
        for (int ks = 0; ks < 4; ++ks) {
            afrag[tile][ks]     = *(const bf16x8*)(s0 + ks * 32);
            afrag[tile][4 + ks] = *(const bf16x8*)(s1 + ks * 32);
        }
    }

#pragma unroll
    for (int ct = 0; ct < NCT; ++ct) {
        f32x4 acc0 = {0.f, 0.f, 0.f, 0.f};
        f32x4 acc1 = {0.f, 0.f, 0.f, 0.f};
        const u16* wp = &wl[(ct * 16 + cl) * WROW + quad * 8];
#pragma unroll
        for (int ks = 0; ks < KS; ++ks) {
            bf16x8 bfrag = *(const bf16x8*)(wp + ks * 32);
            acc0 = __builtin_amdgcn_mfma_f32_16x16x32_bf16(afrag[0][ks], bfrag, acc0, 0, 0, 0);
            acc1 = __builtin_amdgcn_mfma_f32_16x16x32_bf16(afrag[1][ks], bfrag, acc1, 0, 0, 0);
        }
        int gc = ct * 16 + cl;
        float bv = bias[gc];
#pragma unroll
        for (int tile = 0; tile < 2; ++tile) {
            f32x4 a = tile ? acc1 : acc0;
#pragma unroll
            for (int r = 0; r < 4; ++r) {
                int row = rbase + tile * 16 + quad * 4 + r;
                if (row < nrows)
                    outp[(size_t)row * COLS + gc] = f2bf(fmaxf(a[r] + bv, 0.f));
            }
        }
    }
}

// ---------------------------------------------------------------- dual GEMM (layer 2)
// [outA | outB](bf16) = xb @ Wb.T ; outB += bias. Wb [2*COLS][K] bf16.
template <int K, int COLS>
__global__ __launch_bounds__(256) void gemm_mfma(const u16* __restrict__ xb,
                                                 const u16* __restrict__ Wb,
                                                 const float* __restrict__ bias,
                                                 u16* __restrict__ outA,
                                                 u16* __restrict__ outB,
                                                 int nrows) {
    constexpr int NCOL = 2 * COLS;
    constexpr int NCT  = NCOL / 16;
    constexpr int KS   = K / 32;
    constexpr int WROW = K + 8;
    __shared__ u16 wl[NCOL * WROW];

    const int t = threadIdx.x;
    for (int i = t; i < NCOL * (K / 8); i += 256) {
        int r = i / (K / 8), p = i % (K / 8);
        *(uint4*)&wl[r * WROW + p * 8] = *(const uint4*)&Wb[(size_t)r * K + p * 8];
    }
    __syncthreads();

    const int wv    = t >> 6;
    const int lane  = t & 63;
    const int cl    = lane & 15;
    const int quad  = lane >> 4;
    const int rbase = blockIdx.x * 128 + wv * 32;

    bf16x8 afrag[2][KS];
#pragma unroll
    for (int tile = 0; tile < 2; ++tile) {
        int r = rbase + tile * 16 + cl;
        const u16* src = xb + (size_t)min(r, nrows - 1) * K + quad * 8;
#pragma unroll
        for (int ks = 0; ks < KS; ++ks)
            afrag[tile][ks] = *(const bf16x8*)(src + ks * 32);
    }

#pragma unroll
    for (int ct = 0; ct < NCT; ++ct) {
        f32x4 acc0 = {0.f, 0.f, 0.f, 0.f};
        f32x4 acc1 = {0.f, 0.f, 0.f, 0.f};
        const u16* wp = &wl[(ct * 16 + cl) * WROW + quad * 8];
#pragma unroll
        for (int ks = 0; ks < KS; ++ks) {
            bf16x8 bfrag = *(const bf16x8*)(wp + ks * 32);
            acc0 = __builtin_amdgcn_mfma_f32_16x16x32_bf16(afrag[0][ks], bfrag, acc0, 0, 0, 0);
            acc1 = __builtin_amdgcn_mfma_f32_16x16x32_bf16(afrag[1][ks], bfrag, acc1, 0, 0, 0);
        }
        int gc = ct * 16 + cl;
        bool isA = gc < COLS;
        float bv = isA ? 0.f : bias[gc - COLS];
        u16* dst = isA ? (outA + gc) : (outB + (gc - COLS));
#pragma unroll
        for (int tile = 0; tile < 2; ++tile) {
            f32x4 a = tile ? acc1 : acc0;
#pragma unroll
            for (int r = 0; r < 4; ++r) {
                int row = rbase + tile * 16 + quad * 4 + r;
                if (row < nrows) dst[(size_t)row * COLS] = f2bf(a[r] + bv);
            }
        }
    }
}

// ---------------------------------------------------------------- decode (bf16 z)
// nt on the edge stream only: single-use, non-broadcast (R7 lesson).
__global__ __launch_bounds__(256) void decode(const u16* __restrict__ z,
                                              const int* __restrict__ ei,
                                              float* __restrict__ out, int E, int n) {
    int t = blockIdx.x * 256 + threadIdx.x;
    int e = t >> 3, l = t & 7;
    if (e >= E) return;
    int s = __builtin_nontemporal_load(ei + e);
    int d = __builtin_nontemporal_load(ei + (size_t)E + e);
    float p = 0.f;
    if ((unsigned)s < (unsigned)n && (unsigned)d < (unsigned)n) {
        uint4 a = *(const uint4*)(z + (size_t)s * OUT_C + l * 8);
        uint4 b = *(const uint4*)(z + (size_t)d * OUT_C + l * 8);
        p  = bflo(a.x) * bflo(b.x) + bfhi(a.x) * bfhi(b.x);
        p += bflo(a.y) * bflo(b.y) + bfhi(a.y) * bfhi(b.y);
        p += bflo(a.z) * bflo(b.z) + bfhi(a.z) * bfhi(b.z);
        p += bflo(a.w) * bflo(b.w) + bfhi(a.w) * bfhi(b.w);
    }
    p += __shfl_xor(p, 4);
    p += __shfl_xor(p, 2);
    p += __shfl_xor(p, 1);
    if (l == 0) out[e] = p;
}

// ---------------------------------------------------------------- launch
extern "C" void kernel_launch(void* const* d_in, const int* in_sizes, int n_in,
                              void* d_out, int out_size, void* d_ws, size_t ws_size,
                              hipStream_t stream) {
    const float* x   = (const float*)d_in[0];
    const int*   ei  = (const int*)d_in[1];
    const float* w1l = (const float*)d_in[2];
    const float* w1r = (const float*)d_in[3];
    const float* b1  = (const float*)d_in[4];
    const float* w2l = (const float*)d_in[5];
    const float* w2r = (const float*)d_in[6];
    const float* b2  = (const float*)d_in[7];
    float*       out = (float*)d_out;

    const int N  = in_sizes[0] / IN_C;
    const int E  = in_sizes[1] / 2;
    const int NB = (N + 127) >> 7;           // dst tiles

    auto alignup = [](size_t v) { return (v + 255) & ~(size_t)255; };
    char* p = (char*)d_ws;
    int*      ghist   = (int*)p;      p += alignup((size_t)NB_MAX * 4);
    int*      boff    = (int*)p;      p += alignup((size_t)NB_MAX * 4);
    int*      gcur    = (int*)p;      p += alignup((size_t)NB_MAX * 4);
    unsigned* buckets = (unsigned*)p; p += alignup((size_t)E * 4);
    u16*      Wb1     = (u16*)p;      p += alignup((size_t)HID_C * 2 * IN_C * 2);
    u16*      Wb2     = (u16*)p;      p += alignup((size_t)2 * OUT_C * HID_C * 2);
    u16*      xb      = (u16*)p;      p += alignup((size_t)N * IN_C * 2);
    u16*      ag1     = (u16*)p;      p += alignup((size_t)N * HID_C * 2);
    u16*      hb      = (u16*)p;      p += alignup((size_t)N * HID_C * 2);
    u16*      hlb     = (u16*)p;      p += alignup((size_t)N * OUT_C * 2);
    u16*      hrb     = (u16*)p;      p += alignup((size_t)N * OUT_C * 2);
    u16*      zb      = (u16*)p;      p += alignup((size_t)N * OUT_C * 2);

    // converts (independent of buckets)
    cvt_x<<<(N * IN_C / 4 + 255) / 256, 256, 0, stream>>>(x, xb, N * IN_C / 4);
    cvt_w<<<192, 256, 0, stream>>>(w1l, w1r, w2l, w2r, Wb1, Wb2);

    // bucket build
    hipMemsetAsync(ghist, 0, (size_t)NB * 4, stream);
    bucket_hist<<<NFILL, 256, 0, stream>>>(ei + (size_t)E, ghist, E, NB);
    bucket_scan<<<1, 256, 0, stream>>>(ghist, boff, gcur, NB);
    bucket_fill<<<NFILL, 256, 0, stream>>>(ei, gcur, buckets, E, NB);

    const int rb = (N + 127) / 128;

    // ag1 = mean_agg(xb)   (register-scan per dst tile)
    agg_scan<HID_C, false><<<NB, 256, 0, stream>>>(xb, nullptr, boff, ghist,
                                                   buckets, ag1, N);
    // h = relu([ag1|xb] @ [w1l|w1r].T + b1)
    gemm_l1<<<rb, 256, 0, stream>>>(ag1, xb, Wb1, b1, hb, N);

    // hl = h@w2l.T ; hr = h@w2r.T + b2
    gemm_mfma<HID_C, OUT_C><<<rb, 256, 0, stream>>>(hb, Wb2, b2, hlb, hrb, N);
    // z = mean_agg(hl) + hr  (bf16)
    agg_scan<OUT_C, true><<<NB, 256, 0, stream>>>(hlb, hrb, boff, ghist,
                                                  buckets, zb, N);

    // decode (bf16 z)
    decode<<<((size_t)E * 8 + 255) / 256, 256, 0, stream>>>(zb, ei, out, E, N);
}